// Round 1
// baseline (442.437 us; speedup 1.0000x reference)
//
#include <hip/hip_runtime.h>

// o_x[r,c] = l_xx*X[r,c] + g_xx*sumX[r] + g_yx*sumY[r]
// o_y[r,c] = l_yy*Y[r,c] + g_yy*sumY[r] + g_xy*sumX[r]
// R=8192 rows, N=4096 cols. One block per row; 256 threads * 16 floats = 4096.

constexpr int N_COLS = 4096;

__global__ __launch_bounds__(256) void pequinn_rowaffine(
    const float* __restrict__ X, const float* __restrict__ Y,
    const float* __restrict__ p_lxx, const float* __restrict__ p_lyy,
    const float* __restrict__ p_gxx, const float* __restrict__ p_gxy,
    const float* __restrict__ p_gyx, const float* __restrict__ p_gyy,
    float* __restrict__ o_x, float* __restrict__ o_y)
{
    const int row = blockIdx.x;
    const int tid = threadIdx.x;            // 0..255
    const size_t base = (size_t)row * N_COLS;

    const float4* Xr = (const float4*)(X + base);
    const float4* Yr = (const float4*)(Y + base);

    // Load a full row of X and Y into registers (4 x float4 per thread),
    // accumulate partial sums on the way.
    float4 xv[4], yv[4];
    float sx = 0.f, sy = 0.f;
#pragma unroll
    for (int i = 0; i < 4; ++i) {
        const int idx = tid + 256 * i;      // coalesced: lane i -> float4 i
        xv[i] = Xr[idx];
        yv[i] = Yr[idx];
        sx += (xv[i].x + xv[i].y) + (xv[i].z + xv[i].w);
        sy += (yv[i].x + yv[i].y) + (yv[i].z + yv[i].w);
    }

    // Wave-64 butterfly reduce.
#pragma unroll
    for (int off = 32; off > 0; off >>= 1) {
        sx += __shfl_down(sx, off, 64);
        sy += __shfl_down(sy, off, 64);
    }

    // Cross-wave combine via LDS (4 waves / block).
    __shared__ float ssx[4], ssy[4];
    const int wave = tid >> 6;
    const int lane = tid & 63;
    if (lane == 0) { ssx[wave] = sx; ssy[wave] = sy; }
    __syncthreads();
    const float SX = (ssx[0] + ssx[1]) + (ssx[2] + ssx[3]);
    const float SY = (ssy[0] + ssy[1]) + (ssy[2] + ssy[3]);

    // Scalar params (wave-uniform loads; cached after first block).
    const float lxx = p_lxx[0], lyy = p_lyy[0];
    const float gxx = p_gxx[0], gxy = p_gxy[0];
    const float gyx = p_gyx[0], gyy = p_gyy[0];

    const float bx = gxx * SX + gyx * SY;   // row-constant term for o_x
    const float by = gyy * SY + gxy * SX;   // row-constant term for o_y

    float4* Ox = (float4*)(o_x + base);
    float4* Oy = (float4*)(o_y + base);
#pragma unroll
    for (int i = 0; i < 4; ++i) {
        const int idx = tid + 256 * i;
        float4 ox, oy;
        ox.x = fmaf(lxx, xv[i].x, bx);
        ox.y = fmaf(lxx, xv[i].y, bx);
        ox.z = fmaf(lxx, xv[i].z, bx);
        ox.w = fmaf(lxx, xv[i].w, bx);
        oy.x = fmaf(lyy, yv[i].x, by);
        oy.y = fmaf(lyy, yv[i].y, by);
        oy.z = fmaf(lyy, yv[i].z, by);
        oy.w = fmaf(lyy, yv[i].w, by);
        Ox[idx] = ox;
        Oy[idx] = oy;
    }
}

extern "C" void kernel_launch(void* const* d_in, const int* in_sizes, int n_in,
                              void* d_out, int out_size, void* d_ws, size_t ws_size,
                              hipStream_t stream) {
    const float* X    = (const float*)d_in[0];
    const float* Y    = (const float*)d_in[1];
    const float* lxx  = (const float*)d_in[2];
    const float* lyy  = (const float*)d_in[3];
    const float* gxx  = (const float*)d_in[4];
    const float* gxy  = (const float*)d_in[5];
    const float* gyx  = (const float*)d_in[6];
    const float* gyy  = (const float*)d_in[7];

    const int R = in_sizes[0] / N_COLS;     // 8192
    float* o_x = (float*)d_out;                       // first output, R*N floats
    float* o_y = (float*)d_out + (size_t)R * N_COLS;  // second output

    pequinn_rowaffine<<<R, 256, 0, stream>>>(X, Y, lxx, lyy, gxx, gxy, gyx, gyy,
                                             o_x, o_y);
}

// Round 2
// 424.653 us; speedup vs baseline: 1.0419x; 1.0419x over previous
//
#include <hip/hip_runtime.h>

// o_x[r,c] = l_xx*X[r,c] + g_xx*sumX[r] + g_yx*sumY[r]
// o_y[r,c] = l_yy*Y[r,c] + g_yy*sumY[r] + g_xy*sumX[r]
// R=8192 rows, N=4096 cols.
// One 1024-thread block per row: 1 float4 of X + 1 float4 of Y per thread.
// Tiny register footprint -> 32 waves/CU (launch_bounds 1024,8), short dep
// chains, nontemporal streaming access (no reuse anywhere).

constexpr int N_COLS = 4096;

typedef float v4f __attribute__((ext_vector_type(4)));

__global__ __launch_bounds__(1024, 8) void pequinn_rowaffine(
    const float* __restrict__ X, const float* __restrict__ Y,
    const float* __restrict__ p_lxx, const float* __restrict__ p_lyy,
    const float* __restrict__ p_gxx, const float* __restrict__ p_gxy,
    const float* __restrict__ p_gyx, const float* __restrict__ p_gyy,
    float* __restrict__ o_x, float* __restrict__ o_y)
{
    const int row = blockIdx.x;
    const int tid = threadIdx.x;            // 0..1023 ; one float4 each
    const size_t base = (size_t)row * N_COLS;

    const v4f* Xr = (const v4f*)(X + base);
    const v4f* Yr = (const v4f*)(Y + base);

    const v4f xv = __builtin_nontemporal_load(Xr + tid);
    const v4f yv = __builtin_nontemporal_load(Yr + tid);

    float sx = (xv.x + xv.y) + (xv.z + xv.w);
    float sy = (yv.x + yv.y) + (yv.z + yv.w);

    // Wave-64 butterfly reduce.
#pragma unroll
    for (int off = 32; off > 0; off >>= 1) {
        sx += __shfl_down(sx, off, 64);
        sy += __shfl_down(sy, off, 64);
    }

    // Cross-wave combine via LDS (16 waves / block).
    __shared__ float ssx[16], ssy[16];
    const int wave = tid >> 6;
    const int lane = tid & 63;
    if (lane == 0) { ssx[wave] = sx; ssy[wave] = sy; }
    __syncthreads();

    float SX = 0.f, SY = 0.f;
#pragma unroll
    for (int i = 0; i < 16; ++i) {          // same-address LDS reads: broadcast
        SX += ssx[i];
        SY += ssy[i];
    }

    // Scalar params (uniform loads, L2-resident after first blocks).
    const float lxx = p_lxx[0], lyy = p_lyy[0];
    const float gxx = p_gxx[0], gxy = p_gxy[0];
    const float gyx = p_gyx[0], gyy = p_gyy[0];

    const float bx = gxx * SX + gyx * SY;   // row-constant term for o_x
    const float by = gyy * SY + gxy * SX;   // row-constant term for o_y

    v4f ox, oy;
    ox.x = fmaf(lxx, xv.x, bx);
    ox.y = fmaf(lxx, xv.y, bx);
    ox.z = fmaf(lxx, xv.z, bx);
    ox.w = fmaf(lxx, xv.w, bx);
    oy.x = fmaf(lyy, yv.x, by);
    oy.y = fmaf(lyy, yv.y, by);
    oy.z = fmaf(lyy, yv.z, by);
    oy.w = fmaf(lyy, yv.w, by);

    __builtin_nontemporal_store(ox, (v4f*)(o_x + base) + tid);
    __builtin_nontemporal_store(oy, (v4f*)(o_y + base) + tid);
}

extern "C" void kernel_launch(void* const* d_in, const int* in_sizes, int n_in,
                              void* d_out, int out_size, void* d_ws, size_t ws_size,
                              hipStream_t stream) {
    const float* X    = (const float*)d_in[0];
    const float* Y    = (const float*)d_in[1];
    const float* lxx  = (const float*)d_in[2];
    const float* lyy  = (const float*)d_in[3];
    const float* gxx  = (const float*)d_in[4];
    const float* gxy  = (const float*)d_in[5];
    const float* gyx  = (const float*)d_in[6];
    const float* gyy  = (const float*)d_in[7];

    const int R = in_sizes[0] / N_COLS;     // 8192
    float* o_x = (float*)d_out;                       // first output, R*N floats
    float* o_y = (float*)d_out + (size_t)R * N_COLS;  // second output

    pequinn_rowaffine<<<R, 1024, 0, stream>>>(X, Y, lxx, lyy, gxx, gxy, gyx, gyy,
                                              o_x, o_y);
}